// Round 4
// baseline (323.601 us; speedup 1.0000x reference)
//
#include <hip/hip_runtime.h>
#include <math.h>

#define N_NODES 50000
#define N_EDGES 400000
#define N_TOT   450000   /* edges + self-loops */
#define NEG 0.2f

typedef __attribute__((ext_vector_type(8))) short bf16x8;
typedef __attribute__((ext_vector_type(4))) float f32x4;

__device__ __forceinline__ float lrelu(float x) { return x > 0.f ? x : NEG * x; }

__device__ __forceinline__ unsigned short f2bf(float f) {
    unsigned u = __float_as_uint(f);
    unsigned r = u + 0x7FFFu + ((u >> 16) & 1u);   /* RNE */
    return (unsigned short)(r >> 16);
}
__device__ __forceinline__ float bf2f(unsigned short h) {
    return __uint_as_float(((unsigned)h) << 16);
}

/* ---------------- CSR build (by destination) ---------------- */

__global__ void k_zero(int* p, int n) {
    int i = blockIdx.x * blockDim.x + threadIdx.x;
    if (i < n) p[i] = 0;
}

__global__ void k_hist(const int* ei, int* counts) {
    int i = blockIdx.x * blockDim.x + threadIdx.x;
    if (i >= N_TOT) return;
    int dst = (i < N_EDGES) ? ei[N_EDGES + i] : (i - N_EDGES);
    atomicAdd(&counts[dst], 1);
}

__global__ void k_scan1(const int* counts, int* rowptr, int* bsums) {
    __shared__ int sh[256];
    int t = threadIdx.x;
    int base = blockIdx.x * 1024;
    int idx0 = base + t * 4;
    int v[4];
#pragma unroll
    for (int i = 0; i < 4; i++) { int idx = idx0 + i; v[i] = (idx < N_NODES) ? counts[idx] : 0; }
    v[1] += v[0]; v[2] += v[1]; v[3] += v[2];
    int incl = v[3];
    sh[t] = incl;
    __syncthreads();
    for (int off = 1; off < 256; off <<= 1) {
        int add = (t >= off) ? sh[t - off] : 0;
        __syncthreads();
        incl += add;
        sh[t] = incl;
        __syncthreads();
    }
    int excl = incl - v[3];
#pragma unroll
    for (int i = 0; i < 4; i++) { int idx = idx0 + i; if (idx < N_NODES) rowptr[idx + 1] = v[i] + excl; }
    if (t == 255) bsums[blockIdx.x] = incl;
}

__global__ void k_scan2(int* bsums, int nb) {
    int l = threadIdx.x;
    int v = (l < nb) ? bsums[l] : 0;
    int orig = v;
    for (int off = 1; off < 64; off <<= 1) {
        int u = __shfl_up(v, off, 64);
        if (l >= off) v += u;
    }
    if (l < nb) bsums[l] = v - orig;
}

__global__ void k_scan3(int* rowptr, const int* bsums) {
    int i = blockIdx.x * blockDim.x + threadIdx.x;
    if (i == 0) rowptr[0] = 0;
    if (i < N_NODES) rowptr[i + 1] += bsums[i / 1024];
}

__global__ void k_scatter(const int* ei, const int* rowptr, int* cursor, int* colsrc) {
    int i = blockIdx.x * blockDim.x + threadIdx.x;
    if (i >= N_TOT) return;
    int src, dst;
    if (i < N_EDGES) { src = ei[i]; dst = ei[N_EDGES + i]; }
    else             { src = dst = i - N_EDGES; }
    int pos = rowptr[dst] + atomicAdd(&cursor[dst], 1);
    colsrc[pos] = src;
}

/* ---------------- weight pre-split (merged W1+W2): fp32 -> transposed bf16 hi/lo ---------------- */

__global__ void k_prep(const float* __restrict__ W1, unsigned short* W1hiT, unsigned short* W1loT,
                       const float* __restrict__ W2, unsigned short* W2hiT, unsigned short* W2loT) {
    int i = blockIdx.x * 256 + threadIdx.x;
    if (i < 128 * 512) {
        int col = i & 511, k = i >> 9;
        float v = W1[k * 512 + col];
        unsigned short h = f2bf(v);
        W1hiT[col * 128 + k] = h;
        W1loT[col * 128 + k] = f2bf(v - bf2f(h));
    } else if (i < 128 * 512 + 512 * 16) {
        int j = i - 128 * 512;
        int col = j & 15, k = j >> 4;
        float v = W2[k * 16 + col];
        unsigned short h = f2bf(v);
        W2hiT[col * 512 + k] = h;
        W2loT[col * 512 + k] = f2bf(v - bf2f(h));
    }
}

/* ---------------- Layer 1 GEMM via split-bf16 MFMA ----------------
   782 blocks x 256 thr: 64 rows x 512 cols per block (x staged ONCE). */
__global__ __launch_bounds__(256) void k_gemm1(const float* __restrict__ x,
                                               const unsigned short* __restrict__ W1hiT,
                                               const unsigned short* __restrict__ W1loT,
                                               unsigned short* __restrict__ h1b) {
    __shared__ unsigned short xs_hi[64 * 136];
    __shared__ unsigned short xs_lo[64 * 136];
    const int t = threadIdx.x;
    const int rb = blockIdx.x * 64;

#pragma unroll
    for (int i = 0; i < 8; i++) {
        int idx = t + 256 * i;           /* 2048 float4 total */
        int r = idx >> 5;                /* 32 float4 per row */
        int k = (idx & 31) * 4;
        int gr = rb + r;
        float4 v = make_float4(0.f, 0.f, 0.f, 0.f);
        if (gr < N_NODES) v = *reinterpret_cast<const float4*>(&x[gr * 128 + k]);
        ushort4 hi, lo;
        hi.x = f2bf(v.x); lo.x = f2bf(v.x - bf2f(hi.x));
        hi.y = f2bf(v.y); lo.y = f2bf(v.y - bf2f(hi.y));
        hi.z = f2bf(v.z); lo.z = f2bf(v.z - bf2f(hi.z));
        hi.w = f2bf(v.w); lo.w = f2bf(v.w - bf2f(hi.w));
        *reinterpret_cast<ushort4*>(&xs_hi[r * 136 + k]) = hi;
        *reinterpret_cast<ushort4*>(&xs_lo[r * 136 + k]) = lo;
    }
    __syncthreads();

    const int lane = t & 63;
    const int w = t >> 6;
    const int kbase = (lane >> 4) * 8;
    const int colloc = (w << 4) + (lane & 15);

#pragma unroll
    for (int pr = 0; pr < 4; pr++) {
        bf16x8 bhi[2][4], blo[2][4];
#pragma unroll
        for (int si = 0; si < 2; si++) {
            int col = (pr * 2 + si) * 64 + colloc;
#pragma unroll
            for (int kc = 0; kc < 4; kc++) {
                bhi[si][kc] = *reinterpret_cast<const bf16x8*>(&W1hiT[col * 128 + kc * 32 + kbase]);
                blo[si][kc] = *reinterpret_cast<const bf16x8*>(&W1loT[col * 128 + kc * 32 + kbase]);
            }
        }
#pragma unroll
        for (int mt = 0; mt < 4; mt++) {
            const int arow = mt * 16 + (lane & 15);
            bf16x8 ah[4], al[4];
#pragma unroll
            for (int kc = 0; kc < 4; kc++) {
                ah[kc] = *reinterpret_cast<const bf16x8*>(&xs_hi[arow * 136 + kc * 32 + kbase]);
                al[kc] = *reinterpret_cast<const bf16x8*>(&xs_lo[arow * 136 + kc * 32 + kbase]);
            }
#pragma unroll
            for (int si = 0; si < 2; si++) {
                f32x4 acc = {0.f, 0.f, 0.f, 0.f};
#pragma unroll
                for (int kc = 0; kc < 4; kc++) {
                    acc = __builtin_amdgcn_mfma_f32_16x16x32_bf16(ah[kc], bhi[si][kc], acc, 0, 0, 0);
                    acc = __builtin_amdgcn_mfma_f32_16x16x32_bf16(ah[kc], blo[si][kc], acc, 0, 0, 0);
                    acc = __builtin_amdgcn_mfma_f32_16x16x32_bf16(al[kc], bhi[si][kc], acc, 0, 0, 0);
                }
                const int col = (pr * 2 + si) * 64 + colloc;
                const int r0 = rb + mt * 16 + (lane >> 4) * 4;
#pragma unroll
                for (int r = 0; r < 4; r++) {
                    int row = r0 + r;
                    if (row < N_NODES) h1b[row * 512 + col] = f2bf(acc[r]);
                }
            }
        }
    }
}

/* ---------------- attention halves, layer 1: al = einsum(h1, a) ---------------- */
__global__ __launch_bounds__(256) void k_att1(const unsigned short* __restrict__ h1b,
                                              const float* __restrict__ a1s,
                                              const float* __restrict__ a1d,
                                              float* __restrict__ al1s,
                                              float* __restrict__ al1d) {
    int wid = threadIdx.x >> 6, lane = threadIdx.x & 63;
    int n = blockIdx.x * 4 + wid;
    if (n >= N_NODES) return;
    int head = lane >> 3;
    int ch0 = (lane & 7) * 8;
    const float4 s0 = *reinterpret_cast<const float4*>(&a1s[head * 64 + ch0]);
    const float4 s1 = *reinterpret_cast<const float4*>(&a1s[head * 64 + ch0 + 4]);
    const float4 d0 = *reinterpret_cast<const float4*>(&a1d[head * 64 + ch0]);
    const float4 d1 = *reinterpret_cast<const float4*>(&a1d[head * 64 + ch0 + 4]);
    ushort4 hv0 = *reinterpret_cast<const ushort4*>(&h1b[n * 512 + lane * 8]);
    ushort4 hv1 = *reinterpret_cast<const ushort4*>(&h1b[n * 512 + lane * 8 + 4]);
    float ps = bf2f(hv0.x) * s0.x + bf2f(hv0.y) * s0.y + bf2f(hv0.z) * s0.z + bf2f(hv0.w) * s0.w
             + bf2f(hv1.x) * s1.x + bf2f(hv1.y) * s1.y + bf2f(hv1.z) * s1.z + bf2f(hv1.w) * s1.w;
    float pd = bf2f(hv0.x) * d0.x + bf2f(hv0.y) * d0.y + bf2f(hv0.z) * d0.z + bf2f(hv0.w) * d0.w
             + bf2f(hv1.x) * d1.x + bf2f(hv1.y) * d1.y + bf2f(hv1.z) * d1.z + bf2f(hv1.w) * d1.w;
#pragma unroll
    for (int off = 1; off < 8; off <<= 1) {
        ps += __shfl_xor(ps, off, 64);
        pd += __shfl_xor(pd, off, 64);
    }
    if ((lane & 7) == 0) {
        al1s[n * 8 + head] = ps;
        al1d[n * 8 + head] = pd;
    }
}

/* ---------------- Layer 1: softmax + aggregation ----------------
   TWO waves per dst node (256 ch each); each wave computes only its own 4
   heads' weights (16B al1s gather, 4 exp). LDS stride 65 -> conflict-free. */
__global__ __launch_bounds__(256) void k_agg1(const int* __restrict__ rowptr,
                                              const int* __restrict__ colsrc,
                                              const float* __restrict__ al1s,
                                              const float* __restrict__ al1d,
                                              const unsigned short* __restrict__ h1b,
                                              const float* __restrict__ b1,
                                              unsigned short* __restrict__ h1a) {
    __shared__ float pw[4][4 * 65];
    const int t = threadIdx.x;
    const int wv = t >> 6;               /* wave in block 0..3 */
    const int half = wv & 1;             /* channel half */
    const int lane = t & 63;
    const int n = blockIdx.x * 2 + (wv >> 1);
    if (n >= N_NODES) return;
    const int r0 = rowptr[n], r1 = rowptr[n + 1];
    const float4 dd = *reinterpret_cast<const float4*>(&al1d[n * 8 + half * 4]);
    const int hl = lane >> 4;            /* local head 0..3 */
    const int ch = half * 256 + 4 * lane;
    float* mypw = pw[wv];
    f32x4 acc = {0.f, 0.f, 0.f, 0.f};
    float wsum = 0.f;

    for (int base = r0; base < r1; base += 64) {
        int e = base + lane;
        int s0 = 0;
        float p0 = 0.f, p1 = 0.f, p2 = 0.f, p3 = 0.f;
        if (e < r1) {
            s0 = colsrc[e];
            const float4 u = *reinterpret_cast<const float4*>(&al1s[s0 * 8 + half * 4]);
            p0 = __expf(fminf(lrelu(u.x + dd.x), 60.f));
            p1 = __expf(fminf(lrelu(u.y + dd.y), 60.f));
            p2 = __expf(fminf(lrelu(u.z + dd.z), 60.f));
            p3 = __expf(fminf(lrelu(u.w + dd.w), 60.f));
        }
        mypw[0 * 65 + lane] = p0;
        mypw[1 * 65 + lane] = p1;
        mypw[2 * 65 + lane] = p2;
        mypw[3 * 65 + lane] = p3;

        int cnt = min(64, r1 - base);
        for (int j = 0; j < cnt; j++) {
            int s = __shfl(s0, j, 64);
            float w = mypw[hl * 65 + j];
            ushort4 hv = *reinterpret_cast<const ushort4*>(&h1b[s * 512 + ch]);
            wsum += w;
            acc[0] = fmaf(w, bf2f(hv.x), acc[0]);
            acc[1] = fmaf(w, bf2f(hv.y), acc[1]);
            acc[2] = fmaf(w, bf2f(hv.z), acc[2]);
            acc[3] = fmaf(w, bf2f(hv.w), acc[3]);
        }
    }
    float inv = 1.f / wsum;
    const float4 bb = *reinterpret_cast<const float4*>(&b1[ch]);
    float v0 = acc[0] * inv + bb.x;
    float v1 = acc[1] * inv + bb.y;
    float v2 = acc[2] * inv + bb.z;
    float v3 = acc[3] * inv + bb.w;
    v0 = v0 > 0.f ? v0 : __expf(v0) - 1.f;
    v1 = v1 > 0.f ? v1 : __expf(v1) - 1.f;
    v2 = v2 > 0.f ? v2 : __expf(v2) - 1.f;
    v3 = v3 > 0.f ? v3 : __expf(v3) - 1.f;
    ushort4 o;
    o.x = f2bf(v0); o.y = f2bf(v1); o.z = f2bf(v2); o.w = f2bf(v3);
    *reinterpret_cast<ushort4*>(&h1a[n * 512 + ch]) = o;
}

/* ---------------- Layer 2 GEMM via MFMA + fused att2 halves ---------------- */
__global__ __launch_bounds__(128) void k_gemm2(const unsigned short* __restrict__ h1a,
                                               const unsigned short* __restrict__ W2hiT,
                                               const unsigned short* __restrict__ W2loT,
                                               const float* __restrict__ a2s,
                                               const float* __restrict__ a2d,
                                               float* __restrict__ h2,
                                               float* __restrict__ al2s,
                                               float* __restrict__ al2d) {
    __shared__ unsigned short as_hi[32 * 520];
    const int t = threadIdx.x;
    const int rb = blockIdx.x * 32;

#pragma unroll
    for (int i = 0; i < 16; i++) {
        int idx = t + 128 * i;           /* 2048 16B-chunks */
        int r = idx >> 6;                /* 64 chunks per row */
        int k8 = (idx & 63) * 8;
        int gr = rb + r;
        uint4 v = make_uint4(0, 0, 0, 0);
        if (gr < N_NODES) v = *reinterpret_cast<const uint4*>(&h1a[gr * 512 + k8]);
        *reinterpret_cast<uint4*>(&as_hi[r * 520 + k8]) = v;
    }
    __syncthreads();

    const int lane = t & 63;
    const int w = t >> 6;
    const int col = lane & 15;
    const int kbase = (lane >> 4) * 8;
    const int arow = (w << 4) + (lane & 15);

    f32x4 acc = {0.f, 0.f, 0.f, 0.f};
#pragma unroll
    for (int kc = 0; kc < 16; kc++) {
        bf16x8 bh = *reinterpret_cast<const bf16x8*>(&W2hiT[col * 512 + kc * 32 + kbase]);
        bf16x8 bl = *reinterpret_cast<const bf16x8*>(&W2loT[col * 512 + kc * 32 + kbase]);
        bf16x8 ah = *reinterpret_cast<const bf16x8*>(&as_hi[arow * 520 + kc * 32 + kbase]);
        acc = __builtin_amdgcn_mfma_f32_16x16x32_bf16(ah, bh, acc, 0, 0, 0);
        acc = __builtin_amdgcn_mfma_f32_16x16x32_bf16(ah, bl, acc, 0, 0, 0);
    }
    const float as_c = a2s[col];
    const float ad_c = a2d[col];
    const int rloc = (w << 4) + (lane >> 4) * 4;
#pragma unroll
    for (int r = 0; r < 4; r++) {
        int row = rb + rloc + r;
        float ps = acc[r] * as_c;
        float pd = acc[r] * ad_c;
        ps += __shfl_xor(ps, 1, 64); pd += __shfl_xor(pd, 1, 64);
        ps += __shfl_xor(ps, 2, 64); pd += __shfl_xor(pd, 2, 64);
        ps += __shfl_xor(ps, 4, 64); pd += __shfl_xor(pd, 4, 64);
        ps += __shfl_xor(ps, 8, 64); pd += __shfl_xor(pd, 8, 64);
        if (row < N_NODES) {
            h2[row * 16 + col] = acc[r];
            if ((lane & 15) == 0) { al2s[row] = ps; al2d[row] = pd; }
        }
    }
}

/* ---------------- Layer 2: single-pass softmax + aggregation -> out ----------------
   One wave per node; weights computed once per edge in registers, shared via shfl;
   4 edges x 16 channels per iteration. */
__global__ __launch_bounds__(256) void k_agg2(const int* __restrict__ rowptr,
                                              const int* __restrict__ colsrc,
                                              const float* __restrict__ al2s,
                                              const float* __restrict__ al2d,
                                              const float* __restrict__ h2,
                                              const float* __restrict__ b2,
                                              float* __restrict__ out) {
    int wv = threadIdx.x >> 6, lane = threadIdx.x & 63;
    int n = blockIdx.x * 4 + wv;
    if (n >= N_NODES) return;
    int r0 = rowptr[n], r1 = rowptr[n + 1];
    float ald = al2d[n];
    int c = lane & 15, q = lane >> 4;
    float acc = 0.f, smL = 0.f;

    for (int base = r0; base < r1; base += 64) {
        int e = base + lane;
        int s0 = 0; float p0 = 0.f;
        if (e < r1) {
            s0 = colsrc[e];
            p0 = __expf(fminf(lrelu(al2s[s0] + ald), 60.f));
        }
        smL += p0;
        int cnt = min(64, r1 - base);
        for (int j4 = 0; j4 < cnt; j4 += 4) {
            int idx = j4 + q;
            int s = __shfl(s0, idx, 64);
            float w = __shfl(p0, idx, 64);
            acc = fmaf(w, h2[s * 16 + c], acc);
        }
    }
    float sm = smL;
#pragma unroll
    for (int off = 1; off < 64; off <<= 1) sm += __shfl_xor(sm, off, 64);
    acc += __shfl_xor(acc, 16, 64);
    acc += __shfl_xor(acc, 32, 64);
    if (q == 0) out[n * 16 + c] = acc / sm + b2[c];
}

/* ---------------- launch ---------------- */
extern "C" void kernel_launch(void* const* d_in, const int* in_sizes, int n_in,
                              void* d_out, int out_size, void* d_ws, size_t ws_size,
                              hipStream_t stream) {
    const float* x   = (const float*)d_in[0];
    const int*   ei  = (const int*)d_in[1];
    const float* W1  = (const float*)d_in[2];
    const float* a1s = (const float*)d_in[3];
    const float* a1d = (const float*)d_in[4];
    const float* b1  = (const float*)d_in[5];
    const float* W2  = (const float*)d_in[6];
    const float* a2s = (const float*)d_in[7];
    const float* a2d = (const float*)d_in[8];
    const float* b2  = (const float*)d_in[9];
    float* out = (float*)d_out;

    char* ws = (char*)d_ws;
    unsigned short* h1b = (unsigned short*)(ws + 0);            /* N*512 bf16 = 51.2 MB */
    unsigned short* h1a = (unsigned short*)(ws + 51200000);     /* N*512 bf16 = 51.2 MB */
    float* h2   = (float*)(ws + 102400000);    /* N*16 f32 */
    float* al1s = (float*)(ws + 105600000);    /* N*8 */
    float* al1d = (float*)(ws + 107200000);    /* N*8 */
    float* al2s = (float*)(ws + 108800000);    /* N */
    float* al2d = (float*)(ws + 109000000);    /* N */
    int* rowptr = (int*)(ws + 109200000);      /* N+1 */
    int* counts = (int*)(ws + 109400004);      /* N */
    int* cursor = (int*)(ws + 109600004);      /* N (contiguous after counts) */
    int* colsrc = (int*)(ws + 109800004);      /* N_TOT */
    int* bsums  = (int*)(ws + 111600004);      /* 49 */
    unsigned short* W1hiT = (unsigned short*)(ws + 111600256);  /* 512x128 bf16 */
    unsigned short* W1loT = (unsigned short*)(ws + 111731328);
    unsigned short* W2hiT = (unsigned short*)(ws + 111900000);  /* 16x512 bf16 */
    unsigned short* W2loT = (unsigned short*)(ws + 111920000);

    /* CSR build */
    k_zero<<<(2 * N_NODES + 255) / 256, 256, 0, stream>>>(counts, 2 * N_NODES);
    k_hist<<<(N_TOT + 255) / 256, 256, 0, stream>>>(ei, counts);
    k_scan1<<<49, 256, 0, stream>>>(counts, rowptr, bsums);
    k_scan2<<<1, 64, 0, stream>>>(bsums, 49);
    k_scan3<<<(N_NODES + 255) / 256, 256, 0, stream>>>(rowptr, bsums);
    k_scatter<<<(N_TOT + 255) / 256, 256, 0, stream>>>(ei, rowptr, cursor, colsrc);

    /* weight prep (W1 + W2 merged) */
    k_prep<<<288, 256, 0, stream>>>(W1, W1hiT, W1loT, W2, W2hiT, W2loT);

    /* layer 1 */
    k_gemm1<<<(N_NODES + 63) / 64, 256, 0, stream>>>(x, W1hiT, W1loT, h1b);
    k_att1<<<(N_NODES + 3) / 4, 256, 0, stream>>>(h1b, a1s, a1d, al1s, al1d);
    k_agg1<<<(N_NODES + 1) / 2, 256, 0, stream>>>(rowptr, colsrc, al1s, al1d, h1b, b1, h1a);

    /* layer 2 */
    k_gemm2<<<(N_NODES + 31) / 32, 128, 0, stream>>>(h1a, W2hiT, W2loT, a2s, a2d, h2, al2s, al2d);
    k_agg2<<<(N_NODES + 3) / 4, 256, 0, stream>>>(rowptr, colsrc, al2s, al2d, h2, b2, out);
}